// Round 2
// baseline (1939.454 us; speedup 1.0000x reference)
//
#include <hip/hip_runtime.h>
#include <hip/hip_bf16.h>

#define N_NODES 100000
#define N_EDGES 3200000

typedef __hip_bfloat16 bf16;

__device__ __forceinline__ float b2f(bf16 v) { return __bfloat162float(v); }

__device__ __forceinline__ float bits2f(unsigned short w) {
    union { unsigned short u; bf16 b; } c;
    c.u = w;
    return __bfloat162float(c.b);
}

// runtime dtype accessors -------------------------------------------------
__device__ __forceinline__ int get_idx(const void* ei, long long pos, int is64) {
    if (is64) return (int)((const long long*)ei)[pos];
    return ((const int*)ei)[pos];
}
__device__ __forceinline__ float get_f(const void* p, long long pos, int isbf) {
    if (isbf) return b2f(((const bf16*)p)[pos]);
    return ((const float*)p)[pos];
}

// ---------------- dtype detection (1 wave) ----------------
// flags[0] = 1 if float tensors are bf16, 0 if fp32
// flags[1] = 1 if edge_index is int64, 0 if int32
__global__ void detect_kernel(const void* __restrict__ x,
                              const void* __restrict__ ei,
                              int* __restrict__ flags) {
    int lane = threadIdx.x;  // 64 threads
    // float check: EVEN bf16 positions. bf16 data -> real values (~100%
    // plausible); fp32 data -> low mantissa words (~5% plausible).
    const unsigned short* xw = (const unsigned short*)x;
    float v = bits2f(xw[2 * lane]);
    bool plaus = (v == v) && fabsf(v) > 1e-3f && fabsf(v) < 1e2f;
    unsigned long long m1 = __ballot(plaus);
    // int check: ODD int32 positions. int64 data -> all high words zero.
    const int* iw = (const int*)ei;
    bool z = (iw[2 * lane + 1] == 0);
    unsigned long long m2 = __ballot(z);
    if (lane == 0) {
        flags[0] = (__popcll(m1) >= 32) ? 1 : 0;
        flags[1] = (__popcll(m2) == 64) ? 1 : 0;
    }
}

// ---------------- degree histogram ----------------
__global__ void deg_kernel(const void* __restrict__ ei, int* __restrict__ deg,
                           const int* __restrict__ flags) {
    int is64 = flags[1];
    int i = blockIdx.x * blockDim.x + threadIdx.x;
    int stride = gridDim.x * blockDim.x;
    for (; i < N_EDGES; i += stride) {
        atomicAdd(&deg[get_idx(ei, (long long)N_EDGES + i, is64)], 1);
    }
}

// ---------------- layer-1 scatter: sum1[dst] += x[src] (64 ch) ----------------
__global__ void scatter1_kernel(const void* __restrict__ ei,
                                const void* __restrict__ x,
                                float* __restrict__ sum1,
                                const int* __restrict__ flags) {
    int isbf = flags[0];
    int is64 = flags[1];
    int lane = threadIdx.x & 63;
    int wid = (blockIdx.x * blockDim.x + threadIdx.x) >> 6;
    int nwaves = (gridDim.x * blockDim.x) >> 6;
    for (int e = wid; e < N_EDGES; e += nwaves) {
        int s = get_idx(ei, e, is64);
        int d = get_idx(ei, (long long)N_EDGES + e, is64);
        float v = get_f(x, (long long)s * 64 + lane, isbf);
        unsafeAtomicAdd(&sum1[(long long)d * 64 + lane], v);
    }
}

// ---------------- fused node kernel ----------------
// agg = sum1[n]/max(deg,1); h = relu(agg@W1l + b1l + x[n]@W1r)
// z[n] = h@W2l (bf16, gathered by layer-2); r[n] = h@W2r + b2l (bf16)
__global__ __launch_bounds__(256) void node1_kernel(
    const void* __restrict__ x, const float* __restrict__ sum1,
    const int* __restrict__ deg, const void* __restrict__ W1l,
    const void* __restrict__ b1l, const void* __restrict__ W1r,
    const void* __restrict__ W2l, const void* __restrict__ b2l,
    const void* __restrict__ W2r, bf16* __restrict__ zbuf,
    bf16* __restrict__ rbuf, const int* __restrict__ flags) {
    __shared__ float sW1l[64 * 64];
    __shared__ float sW1r[64 * 64];
    __shared__ float sW2l[64 * 32];
    __shared__ float sW2r[64 * 32];

    int isbf = flags[0];
    int t = threadIdx.x;
    for (int i = t; i < 64 * 64; i += 256) {
        sW1l[i] = get_f(W1l, i, isbf);
        sW1r[i] = get_f(W1r, i, isbf);
    }
    for (int i = t; i < 64 * 32; i += 256) {
        sW2l[i] = get_f(W2l, i, isbf);
        sW2r[i] = get_f(W2r, i, isbf);
    }
    __syncthreads();

    int lane = t & 63;
    int gwid = blockIdx.x * 4 + (t >> 6);
    int nwaves = gridDim.x * 4;
    float bias1 = get_f(b1l, lane, isbf);
    float bias2 = (lane >= 32) ? get_f(b2l, lane - 32, isbf) : 0.0f;
    const float* Wp = (lane < 32) ? (sW2l + lane) : (sW2r + (lane - 32));

    for (int n = gwid; n < N_NODES; n += nwaves) {
        float invd = 1.0f / fmaxf((float)deg[n], 1.0f);
        float aggv = sum1[(long long)n * 64 + lane] * invd;
        float xv = get_f(x, (long long)n * 64 + lane, isbf);
        float acc = bias1;
#pragma unroll
        for (int j = 0; j < 64; j++) {
            float aj = __shfl(aggv, j, 64);
            float xj = __shfl(xv, j, 64);
            acc = fmaf(aj, sW1l[j * 64 + lane], acc);
            acc = fmaf(xj, sW1r[j * 64 + lane], acc);
        }
        float h = fmaxf(acc, 0.0f);

        float acc2 = 0.0f;
#pragma unroll
        for (int j = 0; j < 64; j++) {
            float hj = __shfl(h, j, 64);
            acc2 = fmaf(hj, Wp[j * 32], acc2);
        }
        if (lane < 32)
            zbuf[n * 32 + lane] = __float2bfloat16(acc2);
        else
            rbuf[n * 32 + (lane - 32)] = __float2bfloat16(acc2 + bias2);
    }
}

// ---------------- layer-2 scatter: sum2[dst] += z[src] (32 ch) ----------------
__global__ void scatter2_kernel(const void* __restrict__ ei,
                                const bf16* __restrict__ z,
                                float* __restrict__ sum2,
                                const int* __restrict__ flags) {
    int is64 = flags[1];
    int lane = threadIdx.x & 63;
    int wid = (blockIdx.x * blockDim.x + threadIdx.x) >> 6;
    int nwaves = (gridDim.x * blockDim.x) >> 6;
    int c = lane & 31;
    int sub = lane >> 5;
    for (int e2 = wid; e2 < N_EDGES / 2; e2 += nwaves) {
        int e = e2 * 2 + sub;
        int s = get_idx(ei, e, is64);
        int d = get_idx(ei, (long long)N_EDGES + e, is64);
        unsafeAtomicAdd(&sum2[(long long)d * 32 + c], b2f(z[s * 32 + c]));
    }
}

// ---------------- final: out = sum2/max(deg,1) + r ----------------
__global__ void final_kernel(const float* __restrict__ sum2,
                             const bf16* __restrict__ rbuf,
                             const int* __restrict__ deg, void* __restrict__ out,
                             const int* __restrict__ flags) {
    int isbf = flags[0];
    int i = blockIdx.x * blockDim.x + threadIdx.x;
    int stride = gridDim.x * blockDim.x;
    for (; i < N_NODES * 32; i += stride) {
        int n = i >> 5;
        float invd = 1.0f / fmaxf((float)deg[n], 1.0f);
        float val = sum2[i] * invd + b2f(rbuf[i]);
        if (isbf)
            ((bf16*)out)[i] = __float2bfloat16(val);
        else
            ((float*)out)[i] = val;
    }
}

extern "C" void kernel_launch(void* const* d_in, const int* in_sizes, int n_in,
                              void* d_out, int out_size, void* d_ws, size_t ws_size,
                              hipStream_t stream) {
    const void* x = d_in[0];
    const void* ei = d_in[1];  // [2, E]: src = [0,E), dst = [E,2E)
    const void* W1l = d_in[2];
    const void* b1l = d_in[3];
    const void* W1r = d_in[4];
    const void* W2l = d_in[5];
    const void* b2l = d_in[6];
    const void* W2r = d_in[7];

    // workspace layout (bytes), total ~51.7 MB
    char* ws = (char*)d_ws;
    float* sum1 = (float*)ws;                    // N*64 f32 = 25.6 MB
    float* sum2 = (float*)(ws + 25600000);       // N*32 f32 = 12.8 MB
    bf16* zbuf = (bf16*)(ws + 38400000);         // N*32 bf16 = 6.4 MB
    bf16* rbuf = (bf16*)(ws + 44800000);         // N*32 bf16 = 6.4 MB
    int* deg = (int*)(ws + 51200000);            // N i32 = 0.4 MB
    int* flags = (int*)(ws + 51600000);          // 2 i32

    hipMemsetAsync(sum1, 0, (size_t)N_NODES * 64 * 4, stream);
    hipMemsetAsync(sum2, 0, (size_t)N_NODES * 32 * 4, stream);
    hipMemsetAsync(deg, 0, (size_t)N_NODES * 4, stream);

    detect_kernel<<<1, 64, 0, stream>>>(x, ei, flags);
    deg_kernel<<<4096, 256, 0, stream>>>(ei, deg, flags);
    scatter1_kernel<<<8192, 256, 0, stream>>>(ei, x, sum1, flags);
    node1_kernel<<<2048, 256, 0, stream>>>(x, sum1, deg, W1l, b1l, W1r, W2l, b2l,
                                           W2r, zbuf, rbuf, flags);
    scatter2_kernel<<<8192, 256, 0, stream>>>(ei, zbuf, sum2, flags);
    final_kernel<<<4096, 256, 0, stream>>>(sum2, rbuf, deg, d_out, flags);
}